// Round 15
// baseline (2177.167 us; speedup 1.0000x reference)
//
#include <hip/hip_runtime.h>
#include <hip/hip_fp16.h>

// Bidirectional GRU (B=64,S=1024,E=H=256) + FC/ReLU head.
// r15 = r14 + combined-denominator gates (5 trans/output instead of 6:
//   h = [en*(ez+h_old) + (h_old-ez)] / [(en+1)(ez+1)],  en=e^{2an}, ez=e^{-az})
// + restored wave-parity setprio (r10 config). Pipeline unchanged:
//   k_gx0(chunk0) ; k_step(c): [blk 0-7]=rec(c), [8..8+2CT)=gx(c+1),
//                              [8+2CT..)=fc(rows both dirs completed)
//   ; k_fc_tail(remaining rows)
// rec: 8 WGs (2dir x 4bsl) x 512thr, launch_bounds(512,2), W_hh f16 frags
// reg-resident (pre-scaled -log2e / 2log2e, exp2 gates), h in LDS in
// MFMA-A-frag order (linear conflict-free ds_read_b128), ping-pong tiles,
// one lgkm-only raw barrier/step, immediate out16 stores (f16 into d_out;
// fc converts in place to f32 once both directions have written the row).

typedef _Float16 f16x8 __attribute__((ext_vector_type(8)));
typedef _Float16 f16x4 __attribute__((ext_vector_type(4)));
typedef float    f32x4 __attribute__((ext_vector_type(4)));

#define MFMA(a,b,c) __builtin_amdgcn_mfma_f32_16x16x32_f16((a),(b),(c),0,0,0)
#define SWZ(r,c)  ((((r)*512)  + (c)) ^ (((r)&7)<<4))
#define SWZ2(r,c) ((((r)*1024) + (c)) ^ (((r)&7)<<4))
#define NLOG2E (-1.442695041f)
#define P2LOG2E (2.885390082f)

__device__ inline f16x8 pack8(float4 a, float4 b){
  f16x8 h;
  h[0]=(_Float16)a.x; h[1]=(_Float16)a.y; h[2]=(_Float16)a.z; h[3]=(_Float16)a.w;
  h[4]=(_Float16)b.x; h[5]=(_Float16)b.y; h[6]=(_Float16)b.z; h[7]=(_Float16)b.w;
  return h;
}
__device__ inline f16x8 pack8s(float4 a, float4 b, float s){
  f16x8 h;
  h[0]=(_Float16)(a.x*s); h[1]=(_Float16)(a.y*s); h[2]=(_Float16)(a.z*s); h[3]=(_Float16)(a.w*s);
  h[4]=(_Float16)(b.x*s); h[5]=(_Float16)(b.y*s); h[6]=(_Float16)(b.z*s); h[7]=(_Float16)(b.w*s);
  return h;
}

// ---------------- gx body: 512 threads, one (t,dir); waves 4-7 stage-only ----------------
__device__ __forceinline__ void gx_body(
    char* smem, const float* __restrict__ X,
    const float* __restrict__ Wp, const float* __restrict__ bi, const float* __restrict__ bh,
    _Float16* __restrict__ gxc, int CT, int tc, int dir, int t)
{
  _Float16* As = (_Float16*)smem;            // 32KB
  _Float16* Bs = (_Float16*)(smem + 32768);  // 32KB
  const int tid = threadIdx.x;
  #pragma unroll
  for (int i = 0; i < 4; ++i) {              // stage A: rows = batch b, fixed t
    int c = tid + i*512, r = c >> 5, cc = c & 31;
    const float4* s4 = (const float4*)(X + ((size_t)r*1024 + t)*256 + cc*8);
    *(f16x8*)((char*)As + SWZ(r, cc*16)) = pack8(s4[0], s4[1]);
  }
  const int w = tid >> 6, l = tid & 63, lr = l & 15, g = l >> 4;
  const size_t obase = (((size_t)dir*CT + tc)*4 + (w & 3)) * (size_t)12288;
  #pragma unroll 1
  for (int nt = 0; nt < 12; ++nt) {
    __syncthreads();
    #pragma unroll
    for (int i = 0; i < 4; ++i) {            // stage B: W rows nt*64..+64
      int c = tid + i*512, r = c >> 5, cc = c & 31;
      const float4* s4 = (const float4*)(Wp + (size_t)(nt*64 + r)*256 + cc*8);
      *(f16x8*)((char*)Bs + SWZ(r, cc*16)) = pack8(s4[0], s4[1]);
    }
    __syncthreads();
    if (w < 4) {
      f32x4 acc[4];
      #pragma unroll
      for (int ct = 0; ct < 4; ++ct) acc[ct] = (f32x4){0.f,0.f,0.f,0.f};
      #pragma unroll
      for (int kk = 0; kk < 8; ++kk) {
        f16x8 af = *(const f16x8*)((const char*)As + SWZ(w*16 + lr, kk*64 + g*16));
        #pragma unroll
        for (int ct = 0; ct < 4; ++ct) {
          f16x8 bfr = *(const f16x8*)((const char*)Bs + SWZ(ct*16 + lr, kk*64 + g*16));
          acc[ct] = MFMA(af, bfr, acc[ct]);
        }
      }
      #pragma unroll
      for (int ct = 0; ct < 4; ++ct) {       // consumer layout [tid512][3][8]
        const int col = nt*64 + ct*16 + lr;
        const int gate = col >> 8;
        const float sc = (gate == 2) ? P2LOG2E : NLOG2E;
        const float bv = bi[col] + (gate < 2 ? bh[col] : 0.f);
        const int j = col & 255;
        const int tid2 = (j>>5)*64 + g*16 + (j&15);
        const int off = ((j>>4)&1)*4;
        f16x4 v;
        #pragma unroll
        for (int q = 0; q < 4; ++q) v[q] = (_Float16)((acc[ct][q] + bv)*sc);
        *(f16x4*)(gxc + obase + (size_t)tid2*24 + gate*8 + off) = v;
      }
    }
  }
}

// ---------------- fc body: 512 threads, one t; relu(concat_f16 @ Wfc^T + b) in place ----------------
__device__ __forceinline__ void fc_body(
    char* smem, const _Float16* __restrict__ h16, const float* __restrict__ Wfc,
    const float* __restrict__ bfc, float* __restrict__ out, int mt)
{
  _Float16* As = (_Float16*)smem;            // 64KB: [64 rows][512 cols]
  const int tid = threadIdx.x, w = tid >> 6, l = tid & 63;
  const int lr = l & 15, g = l >> 4;
  #pragma unroll
  for (int i = 0; i < 8; ++i) {
    int c = tid + i*512, r = c >> 6, cc = c & 63;
    *(int4*)((char*)As + SWZ2(r, cc*16)) =
        *(const int4*)((const char*)h16 + ((size_t)mt*64 + r)*1024 + cc*16);
  }
  __syncthreads();                           // all h16 reads drained before any store
  const int w4 = w & 3;                      // row-group (rows w4*16..+16)
  const int nb = (w >> 2) * 2;               // nt pair: waves 0-3 -> {0,1}, 4-7 -> {2,3}
  #pragma unroll 1
  for (int ni = 0; ni < 2; ++ni) {
    const int nt = nb + ni;
    f32x4 acc[4];
    #pragma unroll
    for (int ct = 0; ct < 4; ++ct) acc[ct] = (f32x4){0.f,0.f,0.f,0.f};
    #pragma unroll 2
    for (int kk = 0; kk < 16; ++kk) {
      f16x8 af = *(const f16x8*)((const char*)As + SWZ2(w4*16 + lr, kk*64 + g*16));
      #pragma unroll
      for (int ct = 0; ct < 4; ++ct) {
        const float4* s4 = (const float4*)(Wfc + (size_t)(nt*64 + ct*16 + lr)*512 + kk*32 + g*8);
        acc[ct] = MFMA(af, pack8(s4[0], s4[1]), acc[ct]);
      }
    }
    #pragma unroll
    for (int ct = 0; ct < 4; ++ct) {
      const int col = nt*64 + ct*16 + lr;
      const float bv = bfc[col];
      #pragma unroll
      for (int q = 0; q < 4; ++q) {
        const int row = w4*16 + g*4 + q;
        out[((size_t)mt*64 + row)*256 + col] = fmaxf(acc[ct][q] + bv, 0.f);
      }
    }
  }
}

// ---------------- gx prologue kernel (chunk 0) ----------------
__global__ __launch_bounds__(512, 2) void k_gx0(
    const float* __restrict__ X,
    const float* __restrict__ Wf, const float* __restrict__ bihf, const float* __restrict__ bhhf,
    const float* __restrict__ Wb, const float* __restrict__ bihb, const float* __restrict__ bhhb,
    _Float16* __restrict__ gxc, int CT, int sbase)
{
  __shared__ char smem[65536];
  const int tc = blockIdx.x, dir = blockIdx.y;
  const int p = sbase + tc;
  const int t = dir ? (1023 - p) : p;
  gx_body(smem, X, dir ? Wb : Wf, dir ? bihb : bihf, dir ? bhhb : bhhf,
          gxc, CT, tc, dir, t);
}

// ---------------- merged step: rec(c) + gx(c+1) + fc(ready rows) ----------------
__global__ __launch_bounds__(512, 2) void k_step(
    const float* __restrict__ Whh_f, const float* __restrict__ bhh_f,
    const float* __restrict__ Whh_b, const float* __restrict__ bhh_b,
    const _Float16* __restrict__ gxin, float* __restrict__ wsh,
    _Float16* __restrict__ out16, float* __restrict__ hidden,
    int CT, int sbase,
    const float* __restrict__ X,
    const float* __restrict__ Wf, const float* __restrict__ bihf, const float* __restrict__ bhhf,
    const float* __restrict__ Wb, const float* __restrict__ bihb, const float* __restrict__ bhhb,
    _Float16* __restrict__ gxout, int sbase_gx, int gx_valid,
    const float* __restrict__ Wfc, const float* __restrict__ bfc,
    float* __restrict__ outf, int fb1, int fn1, int fb2)
{
  __shared__ char smem[65536];
  if (blockIdx.x >= (unsigned)(8 + 2*CT)) {  // ---- fc role: rows both dirs wrote ----
    const int i = blockIdx.x - (8 + 2*CT);
    const int mt = (i < fn1) ? (fb1 + i) : (fb2 + (i - fn1));
    fc_body(smem, out16, Wfc, bfc, outf, mt);
    return;
  }
  if (blockIdx.x >= 8) {                     // ---- gx role: chunk c+1 ----
    if (!gx_valid) return;
    const int b = blockIdx.x - 8;
    const int tc = b >> 1, dir = b & 1;
    const int p = sbase_gx + tc;
    const int t = dir ? (1023 - p) : p;
    gx_body(smem, X, dir ? Wb : Wf, dir ? bihb : bihf, dir ? bhhb : bhhf,
            gxout, CT, tc, dir, t);
    return;
  }
  // ---- recurrence role (blocks 0-7) ----
  const int dir = blockIdx.x & 1;
  const int bsl = blockIdx.x >> 1;
  const int bbase = bsl * 16;
  const float* __restrict__ Whh = dir ? Whh_b : Whh_f;
  const float* __restrict__ bhh = dir ? bhh_b : bhh_f;
  const int tid = threadIdx.x, w = tid >> 6, l = tid & 63;
  const int lr = l & 15, g = l >> 4;
  const int j0 = w * 32;
  f16x8 wf[6][8];                            // B-frag: W[col][k=kk*32+g*8+i], pre-scaled
  #pragma unroll
  for (int ct = 0; ct < 6; ++ct) {
    const int colg = (ct>>1)*256 + j0 + (ct&1)*16 + lr;
    const float scl = (ct < 4) ? NLOG2E : P2LOG2E;
    #pragma unroll
    for (int kk = 0; kk < 8; ++kk) {
      const float4* s4 = (const float4*)(Whh + (size_t)colg*256 + kk*32 + g*8);
      wf[ct][kk] = pack8s(s4[0], s4[1], scl);
    }
  }
  const float bn0 = P2LOG2E * bhh[512 + j0 + lr];
  const float bn1 = P2LOG2E * bhh[512 + j0 + 16 + lr];
  char* const hsb = smem;                    // ping-pong A-frag h tiles (16KB used)
  char* const afp = hsb + l*16;
  char* const hwp = hsb + w*1024 + (lr>>3)*256 + g*64 + (lr&7)*2;
  float hold[2][4];
  if (sbase == 0) {
    *(int4*)(hsb + tid*16) = make_int4(0,0,0,0);
    #pragma unroll
    for (int jt = 0; jt < 2; ++jt)
      #pragma unroll
      for (int q = 0; q < 4; ++q) hold[jt][q] = 0.f;
  } else {
    const int r = tid >> 5, kq = tid & 31;
    const float4* s4 = (const float4*)(wsh + ((size_t)(dir*64 + bbase + r))*256 + kq*8);
    *(f16x8*)(hsb + (kq>>2)*1024 + (((kq&3)*16) + r)*16) = pack8(s4[0], s4[1]);
    #pragma unroll
    for (int jt = 0; jt < 2; ++jt)
      #pragma unroll
      for (int q = 0; q < 4; ++q)
        hold[jt][q] = wsh[((size_t)(dir*64 + bbase + g*4 + q))*256 + j0 + jt*16 + lr];
  }
  __syncthreads();
  if (w & 1) __builtin_amdgcn_s_setprio(1);  // r10 config (at worst neutral)

  const int t0 = dir ? (1023 - sbase) : sbase;
  char* optr = (char*)out16 + ((size_t)t0*64 + bbase + g*4)*1024
             + (size_t)(dir*256 + j0 + lr)*2;
  const ptrdiff_t ostep = dir ? -(ptrdiff_t)65536 : (ptrdiff_t)65536;
  const _Float16* gp = gxin + ((size_t)(dir*CT)*4 + bsl)*12288 + (size_t)tid*24;
  const ptrdiff_t gstep = 4*12288;

// Gates (combined denominator, 5 trans/output):
//   er = 2^(gv0+ar) = e^{-a_r}; rv = 1/(1+er)
//   en = 2^(fma(rv,an,gv2)) = e^{2 a_n}; ez = 2^(gv1+az) = e^{-a_z}
//   h  = [en*(ez+h_old) + (h_old-ez)] / [(en+1)(ez+1)]
// (limits: en->inf => (ez+h)/(1+ez); ez->0 => h_old; ez->inf => tanh = (en-1)/(en+1))
#define REC_STEP(RB)                                                               \
  {                                                                                \
    const f16x8 gv0 = *(const f16x8*)(gp);                                         \
    const f16x8 gv1 = *(const f16x8*)(gp + 8);                                     \
    const f16x8 gv2 = *(const f16x8*)(gp + 16);                                    \
    gp += gstep;                                                                   \
    {                                                                              \
      f32x4 ar = (f32x4){0.f,0.f,0.f,0.f};                                         \
      f32x4 az = (f32x4){0.f,0.f,0.f,0.f};                                         \
      f32x4 an = (f32x4){bn0,bn0,bn0,bn0};                                         \
      _Pragma("unroll")                                                            \
      for (int kk = 0; kk < 8; ++kk) {                                             \
        const f16x8 af = *(const f16x8*)(afp + (RB)*8192 + kk*1024);               \
        ar = MFMA(af, wf[0][kk], ar);                                              \
        az = MFMA(af, wf[2][kk], az);                                              \
        an = MFMA(af, wf[4][kk], an);                                              \
      }                                                                            \
      _Pragma("unroll")                                                            \
      for (int q = 0; q < 4; ++q) {                                                \
        const float er = __builtin_amdgcn_exp2f((float)gv0[q] + ar[q]);            \
        const float rv = __builtin_amdgcn_rcpf(1.f + er);                          \
        const float en = __builtin_amdgcn_exp2f(                                   \
            __builtin_fmaf(rv, an[q], (float)gv2[q]));                             \
        const float ez = __builtin_amdgcn_exp2f((float)gv1[q] + az[q]);            \
        const float num = __builtin_fmaf(en, ez + hold[0][q], hold[0][q] - ez);    \
        const float den = (en + 1.f) * (ez + 1.f);                                 \
        const float h = num * __builtin_amdgcn_rcpf(den);                          \
        hold[0][q] = h;                                                            \
        const _Float16 hf = (_Float16)h;                                           \
        *(_Float16*)(hwp + ((RB)^1)*8192 + q*16) = hf;                             \
        *(_Float16*)(optr + q*1024) = hf;                                          \
      }                                                                            \
    }                                                                              \
    {                                                                              \
      f32x4 ar = (f32x4){0.f,0.f,0.f,0.f};                                         \
      f32x4 az = (f32x4){0.f,0.f,0.f,0.f};                                         \
      f32x4 an = (f32x4){bn1,bn1,bn1,bn1};                                         \
      _Pragma("unroll")                                                            \
      for (int kk = 0; kk < 8; ++kk) {                                             \
        const f16x8 af = *(const f16x8*)(afp + (RB)*8192 + kk*1024);               \
        ar = MFMA(af, wf[1][kk], ar);                                              \
        az = MFMA(af, wf[3][kk], az);                                              \
        an = MFMA(af, wf[5][kk], an);                                              \
      }                                                                            \
      _Pragma("unroll")                                                            \
      for (int q = 0; q < 4; ++q) {                                                \
        const float er = __builtin_amdgcn_exp2f((float)gv0[4+q] + ar[q]);          \
        const float rv = __builtin_amdgcn_rcpf(1.f + er);                          \
        const float en = __builtin_amdgcn_exp2f(                                   \
            __builtin_fmaf(rv, an[q], (float)gv2[4+q]));                           \
        const float ez = __builtin_amdgcn_exp2f((float)gv1[4+q] + az[q]);          \
        const float num = __builtin_fmaf(en, ez + hold[1][q], hold[1][q] - ez);    \
        const float den = (en + 1.f) * (ez + 1.f);                                 \
        const float h = num * __builtin_amdgcn_rcpf(den);                          \
        hold[1][q] = h;                                                            \
        const _Float16 hf = (_Float16)h;                                           \
        *(_Float16*)(hwp + ((RB)^1)*8192 + 512 + q*16) = hf;                       \
        *(_Float16*)(optr + q*1024 + 32) = hf;                                     \
      }                                                                            \
    }                                                                              \
    optr += ostep;                                                                 \
    asm volatile("s_waitcnt lgkmcnt(0)" ::: "memory");                             \
    __builtin_amdgcn_s_barrier();                                                  \
    asm volatile("" ::: "memory");                                                 \
  }

  #pragma unroll 1
  for (int sc = 0; sc < CT; sc += 2) {
    REC_STEP(0)
    REC_STEP(1)
  }
#undef REC_STEP

  if (sbase + CT == 1024) {                  // final h -> hidden output
    #pragma unroll
    for (int jt = 0; jt < 2; ++jt)
      #pragma unroll
      for (int q = 0; q < 4; ++q)
        hidden[((size_t)(dir*64 + bbase + g*4 + q))*256 + j0 + jt*16 + lr] = hold[jt][q];
  } else {                                   // persist h for next chunk
    #pragma unroll
    for (int jt = 0; jt < 2; ++jt)
      #pragma unroll
      for (int q = 0; q < 4; ++q)
        wsh[((size_t)(dir*64 + bbase + g*4 + q))*256 + j0 + jt*16 + lr] = hold[jt][q];
  }
}

// ---------------- fc tail: remaining rows (two segments) ----------------
__global__ __launch_bounds__(512, 2) void k_fc_tail(
    const _Float16* __restrict__ h16, const float* __restrict__ Wfc,
    const float* __restrict__ bfc, float* __restrict__ out,
    int fb1, int fn1, int fb2)
{
  __shared__ char smem[65536];
  const int i = blockIdx.x;
  const int mt = (i < fn1) ? (fb1 + i) : (fb2 + (i - fn1));
  fc_body(smem, h16, Wfc, bfc, out, mt);
}

extern "C" void kernel_launch(void* const* d_in, const int* in_sizes, int n_in,
                              void* d_out, int out_size, void* d_ws, size_t ws_size,
                              hipStream_t stream) {
  const float* X      = (const float*)d_in[0];
  const float* W_ih_f = (const float*)d_in[1];
  const float* W_hh_f = (const float*)d_in[2];
  const float* b_ih_f = (const float*)d_in[3];
  const float* b_hh_f = (const float*)d_in[4];
  const float* W_ih_b = (const float*)d_in[5];
  const float* W_hh_b = (const float*)d_in[6];
  const float* b_ih_b = (const float*)d_in[7];
  const float* b_hh_b = (const float*)d_in[8];
  const float* W_fc   = (const float*)d_in[9];
  const float* b_fc   = (const float*)d_in[10];

  // gxc double-buffered; ws need = 2*CT*196608 + 131072 (CT=256 -> 100.8MB).
  int CT = 256;
  while (CT > 8 && (2*(size_t)CT*196608 + 131072) > ws_size) CT >>= 1;
  const size_t CTB = (size_t)CT*196608;
  _Float16* buf0 = (_Float16*)d_ws;
  _Float16* buf1 = (_Float16*)((char*)d_ws + CTB);
  float*    wsh  = (float*)((char*)d_ws + 2*CTB);

  _Float16* h16   = (_Float16*)d_out;                  // [1024][64][512] f16 (in-place)
  float*    out   = (float*)d_out;                     // [1024][64][256] f32
  float*    hidden= (float*)d_out + (size_t)1024*64*256;

  const int NC = 1024 / CT;
  k_gx0<<<dim3(CT, 2), dim3(512), 0, stream>>>(X, W_ih_f, b_ih_f, b_hh_f,
                                               W_ih_b, b_ih_b, b_hh_b, buf0, CT, 0);
  int flo = 512, fhi = 512;                  // fc'd interval [flo,fhi)
  for (int c = 0; c < NC; ++c) {
    _Float16* bin  = (c & 1) ? buf1 : buf0;
    _Float16* bout = (c & 1) ? buf0 : buf1;
    // rows complete before this launch: fwd [0,c*CT), bwd [1024-c*CT,1024)
    const int alo = 1024 - c*CT, ahi = c*CT;
    int b1 = 0, n1 = 0, b2 = 0, n2 = 0;
    if (ahi > alo) {
      if (alo < flo) { b1 = alo; n1 = flo - alo; }
      if (ahi > fhi) { b2 = fhi; n2 = ahi - fhi; }
      if (alo < flo) flo = alo;
      if (ahi > fhi) fhi = ahi;
    }
    k_step<<<dim3(8 + 2*CT + n1 + n2), dim3(512), 0, stream>>>(
        W_hh_f, b_hh_f, W_hh_b, b_hh_b, bin, wsh, h16, hidden, CT, c*CT,
        X, W_ih_f, b_ih_f, b_hh_f, W_ih_b, b_ih_b, b_hh_b,
        bout, (c+1)*CT, (c < NC-1) ? 1 : 0,
        W_fc, b_fc, out, b1, n1, b2);
  }
  // tail: [0,flo) and [fhi,1024)
  const int tn1 = flo, tn2 = 1024 - fhi;
  if (tn1 + tn2 > 0)
    k_fc_tail<<<dim3(tn1 + tn2), dim3(512), 0, stream>>>(h16, W_fc, b_fc, out,
                                                         0, tn1, fhi);
}

// Round 16
// 2014.084 us; speedup vs baseline: 1.0810x; 1.0810x over previous
//
#include <hip/hip_runtime.h>
#include <hip/hip_fp16.h>

// Bidirectional GRU (B=64,S=1024,E=H=256) + FC/ReLU head.
// r16 = r14 (best, 2088us) + wave-parity setprio restored (single-variable A/B
// vs r14: isolates whether r10's 478us/dispatch rec owed to setprio).
//   k_gx0(chunk0) ; k_step(c): [blk 0-7]=rec(c), [8..8+2CT)=gx(c+1),
//                              [8+2CT..)=fc(rows both dirs completed)
//   ; k_fc_tail(remaining rows)
// rec: 8 WGs (2dir x 4bsl) x 512thr, launch_bounds(512,2), W_hh f16 frags
// reg-resident (pre-scaled -log2e / 2log2e, exp2 gates, 6-trans short-chain
// form), h in LDS in MFMA-A-frag order (linear conflict-free ds_read_b128),
// ping-pong tiles, one lgkm-only raw barrier/step, immediate out16 stores
// (f16 into d_out; fc converts in place to f32 once both dirs wrote the row).

typedef _Float16 f16x8 __attribute__((ext_vector_type(8)));
typedef _Float16 f16x4 __attribute__((ext_vector_type(4)));
typedef float    f32x4 __attribute__((ext_vector_type(4)));

#define MFMA(a,b,c) __builtin_amdgcn_mfma_f32_16x16x32_f16((a),(b),(c),0,0,0)
#define SWZ(r,c)  ((((r)*512)  + (c)) ^ (((r)&7)<<4))
#define SWZ2(r,c) ((((r)*1024) + (c)) ^ (((r)&7)<<4))
#define NLOG2E (-1.442695041f)
#define P2LOG2E (2.885390082f)

__device__ inline f16x8 pack8(float4 a, float4 b){
  f16x8 h;
  h[0]=(_Float16)a.x; h[1]=(_Float16)a.y; h[2]=(_Float16)a.z; h[3]=(_Float16)a.w;
  h[4]=(_Float16)b.x; h[5]=(_Float16)b.y; h[6]=(_Float16)b.z; h[7]=(_Float16)b.w;
  return h;
}
__device__ inline f16x8 pack8s(float4 a, float4 b, float s){
  f16x8 h;
  h[0]=(_Float16)(a.x*s); h[1]=(_Float16)(a.y*s); h[2]=(_Float16)(a.z*s); h[3]=(_Float16)(a.w*s);
  h[4]=(_Float16)(b.x*s); h[5]=(_Float16)(b.y*s); h[6]=(_Float16)(b.z*s); h[7]=(_Float16)(b.w*s);
  return h;
}

// ---------------- gx body: 512 threads, one (t,dir); waves 4-7 stage-only ----------------
__device__ __forceinline__ void gx_body(
    char* smem, const float* __restrict__ X,
    const float* __restrict__ Wp, const float* __restrict__ bi, const float* __restrict__ bh,
    _Float16* __restrict__ gxc, int CT, int tc, int dir, int t)
{
  _Float16* As = (_Float16*)smem;            // 32KB
  _Float16* Bs = (_Float16*)(smem + 32768);  // 32KB
  const int tid = threadIdx.x;
  #pragma unroll
  for (int i = 0; i < 4; ++i) {              // stage A: rows = batch b, fixed t
    int c = tid + i*512, r = c >> 5, cc = c & 31;
    const float4* s4 = (const float4*)(X + ((size_t)r*1024 + t)*256 + cc*8);
    *(f16x8*)((char*)As + SWZ(r, cc*16)) = pack8(s4[0], s4[1]);
  }
  const int w = tid >> 6, l = tid & 63, lr = l & 15, g = l >> 4;
  const size_t obase = (((size_t)dir*CT + tc)*4 + (w & 3)) * (size_t)12288;
  #pragma unroll 1
  for (int nt = 0; nt < 12; ++nt) {
    __syncthreads();
    #pragma unroll
    for (int i = 0; i < 4; ++i) {            // stage B: W rows nt*64..+64
      int c = tid + i*512, r = c >> 5, cc = c & 31;
      const float4* s4 = (const float4*)(Wp + (size_t)(nt*64 + r)*256 + cc*8);
      *(f16x8*)((char*)Bs + SWZ(r, cc*16)) = pack8(s4[0], s4[1]);
    }
    __syncthreads();
    if (w < 4) {
      f32x4 acc[4];
      #pragma unroll
      for (int ct = 0; ct < 4; ++ct) acc[ct] = (f32x4){0.f,0.f,0.f,0.f};
      #pragma unroll
      for (int kk = 0; kk < 8; ++kk) {
        f16x8 af = *(const f16x8*)((const char*)As + SWZ(w*16 + lr, kk*64 + g*16));
        #pragma unroll
        for (int ct = 0; ct < 4; ++ct) {
          f16x8 bfr = *(const f16x8*)((const char*)Bs + SWZ(ct*16 + lr, kk*64 + g*16));
          acc[ct] = MFMA(af, bfr, acc[ct]);
        }
      }
      #pragma unroll
      for (int ct = 0; ct < 4; ++ct) {       // consumer layout [tid512][3][8]
        const int col = nt*64 + ct*16 + lr;
        const int gate = col >> 8;
        const float sc = (gate == 2) ? P2LOG2E : NLOG2E;
        const float bv = bi[col] + (gate < 2 ? bh[col] : 0.f);
        const int j = col & 255;
        const int tid2 = (j>>5)*64 + g*16 + (j&15);
        const int off = ((j>>4)&1)*4;
        f16x4 v;
        #pragma unroll
        for (int q = 0; q < 4; ++q) v[q] = (_Float16)((acc[ct][q] + bv)*sc);
        *(f16x4*)(gxc + obase + (size_t)tid2*24 + gate*8 + off) = v;
      }
    }
  }
}

// ---------------- fc body: 512 threads, one t; relu(concat_f16 @ Wfc^T + b) in place ----------------
__device__ __forceinline__ void fc_body(
    char* smem, const _Float16* __restrict__ h16, const float* __restrict__ Wfc,
    const float* __restrict__ bfc, float* __restrict__ out, int mt)
{
  _Float16* As = (_Float16*)smem;            // 64KB: [64 rows][512 cols]
  const int tid = threadIdx.x, w = tid >> 6, l = tid & 63;
  const int lr = l & 15, g = l >> 4;
  #pragma unroll
  for (int i = 0; i < 8; ++i) {
    int c = tid + i*512, r = c >> 6, cc = c & 63;
    *(int4*)((char*)As + SWZ2(r, cc*16)) =
        *(const int4*)((const char*)h16 + ((size_t)mt*64 + r)*1024 + cc*16);
  }
  __syncthreads();                           // all h16 reads drained before any store
  const int w4 = w & 3;                      // row-group (rows w4*16..+16)
  const int nb = (w >> 2) * 2;               // nt pair: waves 0-3 -> {0,1}, 4-7 -> {2,3}
  #pragma unroll 1
  for (int ni = 0; ni < 2; ++ni) {
    const int nt = nb + ni;
    f32x4 acc[4];
    #pragma unroll
    for (int ct = 0; ct < 4; ++ct) acc[ct] = (f32x4){0.f,0.f,0.f,0.f};
    #pragma unroll 2
    for (int kk = 0; kk < 16; ++kk) {
      f16x8 af = *(const f16x8*)((const char*)As + SWZ2(w4*16 + lr, kk*64 + g*16));
      #pragma unroll
      for (int ct = 0; ct < 4; ++ct) {
        const float4* s4 = (const float4*)(Wfc + (size_t)(nt*64 + ct*16 + lr)*512 + kk*32 + g*8);
        acc[ct] = MFMA(af, pack8(s4[0], s4[1]), acc[ct]);
      }
    }
    #pragma unroll
    for (int ct = 0; ct < 4; ++ct) {
      const int col = nt*64 + ct*16 + lr;
      const float bv = bfc[col];
      #pragma unroll
      for (int q = 0; q < 4; ++q) {
        const int row = w4*16 + g*4 + q;
        out[((size_t)mt*64 + row)*256 + col] = fmaxf(acc[ct][q] + bv, 0.f);
      }
    }
  }
}

// ---------------- gx prologue kernel (chunk 0) ----------------
__global__ __launch_bounds__(512, 2) void k_gx0(
    const float* __restrict__ X,
    const float* __restrict__ Wf, const float* __restrict__ bihf, const float* __restrict__ bhhf,
    const float* __restrict__ Wb, const float* __restrict__ bihb, const float* __restrict__ bhhb,
    _Float16* __restrict__ gxc, int CT, int sbase)
{
  __shared__ char smem[65536];
  const int tc = blockIdx.x, dir = blockIdx.y;
  const int p = sbase + tc;
  const int t = dir ? (1023 - p) : p;
  gx_body(smem, X, dir ? Wb : Wf, dir ? bihb : bihf, dir ? bhhb : bhhf,
          gxc, CT, tc, dir, t);
}

// ---------------- merged step: rec(c) + gx(c+1) + fc(ready rows) ----------------
__global__ __launch_bounds__(512, 2) void k_step(
    const float* __restrict__ Whh_f, const float* __restrict__ bhh_f,
    const float* __restrict__ Whh_b, const float* __restrict__ bhh_b,
    const _Float16* __restrict__ gxin, float* __restrict__ wsh,
    _Float16* __restrict__ out16, float* __restrict__ hidden,
    int CT, int sbase,
    const float* __restrict__ X,
    const float* __restrict__ Wf, const float* __restrict__ bihf, const float* __restrict__ bhhf,
    const float* __restrict__ Wb, const float* __restrict__ bihb, const float* __restrict__ bhhb,
    _Float16* __restrict__ gxout, int sbase_gx, int gx_valid,
    const float* __restrict__ Wfc, const float* __restrict__ bfc,
    float* __restrict__ outf, int fb1, int fn1, int fb2)
{
  __shared__ char smem[65536];
  if (blockIdx.x >= (unsigned)(8 + 2*CT)) {  // ---- fc role: rows both dirs wrote ----
    const int i = blockIdx.x - (8 + 2*CT);
    const int mt = (i < fn1) ? (fb1 + i) : (fb2 + (i - fn1));
    fc_body(smem, out16, Wfc, bfc, outf, mt);
    return;
  }
  if (blockIdx.x >= 8) {                     // ---- gx role: chunk c+1 ----
    if (!gx_valid) return;
    const int b = blockIdx.x - 8;
    const int tc = b >> 1, dir = b & 1;
    const int p = sbase_gx + tc;
    const int t = dir ? (1023 - p) : p;
    gx_body(smem, X, dir ? Wb : Wf, dir ? bihb : bihf, dir ? bhhb : bhhf,
            gxout, CT, tc, dir, t);
    return;
  }
  // ---- recurrence role (blocks 0-7) ----
  const int dir = blockIdx.x & 1;
  const int bsl = blockIdx.x >> 1;
  const int bbase = bsl * 16;
  const float* __restrict__ Whh = dir ? Whh_b : Whh_f;
  const float* __restrict__ bhh = dir ? bhh_b : bhh_f;
  const int tid = threadIdx.x, w = tid >> 6, l = tid & 63;
  const int lr = l & 15, g = l >> 4;
  const int j0 = w * 32;
  f16x8 wf[6][8];                            // B-frag: W[col][k=kk*32+g*8+i], pre-scaled
  #pragma unroll
  for (int ct = 0; ct < 6; ++ct) {
    const int colg = (ct>>1)*256 + j0 + (ct&1)*16 + lr;
    const float scl = (ct < 4) ? NLOG2E : P2LOG2E;
    #pragma unroll
    for (int kk = 0; kk < 8; ++kk) {
      const float4* s4 = (const float4*)(Whh + (size_t)colg*256 + kk*32 + g*8);
      wf[ct][kk] = pack8s(s4[0], s4[1], scl);
    }
  }
  const float bn0 = P2LOG2E * bhh[512 + j0 + lr];
  const float bn1 = P2LOG2E * bhh[512 + j0 + 16 + lr];
  char* const hsb = smem;                    // ping-pong A-frag h tiles (16KB used)
  char* const afp = hsb + l*16;
  char* const hwp = hsb + w*1024 + (lr>>3)*256 + g*64 + (lr&7)*2;
  float hold[2][4];
  if (sbase == 0) {
    *(int4*)(hsb + tid*16) = make_int4(0,0,0,0);
    #pragma unroll
    for (int jt = 0; jt < 2; ++jt)
      #pragma unroll
      for (int q = 0; q < 4; ++q) hold[jt][q] = 0.f;
  } else {
    const int r = tid >> 5, kq = tid & 31;
    const float4* s4 = (const float4*)(wsh + ((size_t)(dir*64 + bbase + r))*256 + kq*8);
    *(f16x8*)(hsb + (kq>>2)*1024 + (((kq&3)*16) + r)*16) = pack8(s4[0], s4[1]);
    #pragma unroll
    for (int jt = 0; jt < 2; ++jt)
      #pragma unroll
      for (int q = 0; q < 4; ++q)
        hold[jt][q] = wsh[((size_t)(dir*64 + bbase + g*4 + q))*256 + j0 + jt*16 + lr];
  }
  __syncthreads();
  if (w & 1) __builtin_amdgcn_s_setprio(1);  // r10 config — the A/B variable

  const int t0 = dir ? (1023 - sbase) : sbase;
  char* optr = (char*)out16 + ((size_t)t0*64 + bbase + g*4)*1024
             + (size_t)(dir*256 + j0 + lr)*2;
  const ptrdiff_t ostep = dir ? -(ptrdiff_t)65536 : (ptrdiff_t)65536;
  const _Float16* gp = gxin + ((size_t)(dir*CT)*4 + bsl)*12288 + (size_t)tid*24;
  const ptrdiff_t gstep = 4*12288;

#define REC_STEP(RB)                                                               \
  {                                                                                \
    const f16x8 gv0 = *(const f16x8*)(gp);                                         \
    const f16x8 gv1 = *(const f16x8*)(gp + 8);                                     \
    const f16x8 gv2 = *(const f16x8*)(gp + 16);                                    \
    gp += gstep;                                                                   \
    {                                                                              \
      f32x4 ar = (f32x4){0.f,0.f,0.f,0.f};                                         \
      f32x4 az = (f32x4){0.f,0.f,0.f,0.f};                                         \
      f32x4 an = (f32x4){bn0,bn0,bn0,bn0};                                         \
      _Pragma("unroll")                                                            \
      for (int kk = 0; kk < 8; ++kk) {                                             \
        const f16x8 af = *(const f16x8*)(afp + (RB)*8192 + kk*1024);               \
        ar = MFMA(af, wf[0][kk], ar);                                              \
        az = MFMA(af, wf[2][kk], az);                                              \
        an = MFMA(af, wf[4][kk], an);                                              \
      }                                                                            \
      _Pragma("unroll")                                                            \
      for (int q = 0; q < 4; ++q) {                                                \
        const float rv = __builtin_amdgcn_rcpf(                                    \
            1.f + __builtin_amdgcn_exp2f((float)gv0[q] + ar[q]));                  \
        const float zv = __builtin_amdgcn_rcpf(                                    \
            1.f + __builtin_amdgcn_exp2f((float)gv1[q] + az[q]));                  \
        const float nv = __builtin_fmaf(-2.f, __builtin_amdgcn_rcpf(               \
            1.f + __builtin_amdgcn_exp2f(                                          \
                __builtin_fmaf(rv, an[q], (float)gv2[q]))), 1.f);                  \
        const float h = __builtin_fmaf(zv, hold[0][q] - nv, nv);                   \
        hold[0][q] = h;                                                            \
        const _Float16 hf = (_Float16)h;                                           \
        *(_Float16*)(hwp + ((RB)^1)*8192 + q*16) = hf;                             \
        *(_Float16*)(optr + q*1024) = hf;                                          \
      }                                                                            \
    }                                                                              \
    {                                                                              \
      f32x4 ar = (f32x4){0.f,0.f,0.f,0.f};                                         \
      f32x4 az = (f32x4){0.f,0.f,0.f,0.f};                                         \
      f32x4 an = (f32x4){bn1,bn1,bn1,bn1};                                         \
      _Pragma("unroll")                                                            \
      for (int kk = 0; kk < 8; ++kk) {                                             \
        const f16x8 af = *(const f16x8*)(afp + (RB)*8192 + kk*1024);               \
        ar = MFMA(af, wf[1][kk], ar);                                              \
        az = MFMA(af, wf[3][kk], az);                                              \
        an = MFMA(af, wf[5][kk], an);                                              \
      }                                                                            \
      _Pragma("unroll")                                                            \
      for (int q = 0; q < 4; ++q) {                                                \
        const float rv = __builtin_amdgcn_rcpf(                                    \
            1.f + __builtin_amdgcn_exp2f((float)gv0[4+q] + ar[q]));                \
        const float zv = __builtin_amdgcn_rcpf(                                    \
            1.f + __builtin_amdgcn_exp2f((float)gv1[4+q] + az[q]));                \
        const float nv = __builtin_fmaf(-2.f, __builtin_amdgcn_rcpf(               \
            1.f + __builtin_amdgcn_exp2f(                                          \
                __builtin_fmaf(rv, an[q], (float)gv2[4+q]))), 1.f);                \
        const float h = __builtin_fmaf(zv, hold[1][q] - nv, nv);                   \
        hold[1][q] = h;                                                            \
        const _Float16 hf = (_Float16)h;                                           \
        *(_Float16*)(hwp + ((RB)^1)*8192 + 512 + q*16) = hf;                       \
        *(_Float16*)(optr + q*1024 + 32) = hf;                                     \
      }                                                                            \
    }                                                                              \
    optr += ostep;                                                                 \
    asm volatile("s_waitcnt lgkmcnt(0)" ::: "memory");                             \
    __builtin_amdgcn_s_barrier();                                                  \
    asm volatile("" ::: "memory");                                                 \
  }

  #pragma unroll 1
  for (int sc = 0; sc < CT; sc += 2) {
    REC_STEP(0)
    REC_STEP(1)
  }
#undef REC_STEP

  if (sbase + CT == 1024) {                  // final h -> hidden output
    #pragma unroll
    for (int jt = 0; jt < 2; ++jt)
      #pragma unroll
      for (int q = 0; q < 4; ++q)
        hidden[((size_t)(dir*64 + bbase + g*4 + q))*256 + j0 + jt*16 + lr] = hold[jt][q];
  } else {                                   // persist h for next chunk
    #pragma unroll
    for (int jt = 0; jt < 2; ++jt)
      #pragma unroll
      for (int q = 0; q < 4; ++q)
        wsh[((size_t)(dir*64 + bbase + g*4 + q))*256 + j0 + jt*16 + lr] = hold[jt][q];
  }
}

// ---------------- fc tail: remaining rows (two segments) ----------------
__global__ __launch_bounds__(512, 2) void k_fc_tail(
    const _Float16* __restrict__ h16, const float* __restrict__ Wfc,
    const float* __restrict__ bfc, float* __restrict__ out,
    int fb1, int fn1, int fb2)
{
  __shared__ char smem[65536];
  const int i = blockIdx.x;
  const int mt = (i < fn1) ? (fb1 + i) : (fb2 + (i - fn1));
  fc_body(smem, h16, Wfc, bfc, out, mt);
}

extern "C" void kernel_launch(void* const* d_in, const int* in_sizes, int n_in,
                              void* d_out, int out_size, void* d_ws, size_t ws_size,
                              hipStream_t stream) {
  const float* X      = (const float*)d_in[0];
  const float* W_ih_f = (const float*)d_in[1];
  const float* W_hh_f = (const float*)d_in[2];
  const float* b_ih_f = (const float*)d_in[3];
  const float* b_hh_f = (const float*)d_in[4];
  const float* W_ih_b = (const float*)d_in[5];
  const float* W_hh_b = (const float*)d_in[6];
  const float* b_ih_b = (const float*)d_in[7];
  const float* b_hh_b = (const float*)d_in[8];
  const float* W_fc   = (const float*)d_in[9];
  const float* b_fc   = (const float*)d_in[10];

  // gxc double-buffered; ws need = 2*CT*196608 + 131072 (CT=256 -> 100.8MB).
  int CT = 256;
  while (CT > 8 && (2*(size_t)CT*196608 + 131072) > ws_size) CT >>= 1;
  const size_t CTB = (size_t)CT*196608;
  _Float16* buf0 = (_Float16*)d_ws;
  _Float16* buf1 = (_Float16*)((char*)d_ws + CTB);
  float*    wsh  = (float*)((char*)d_ws + 2*CTB);

  _Float16* h16   = (_Float16*)d_out;                  // [1024][64][512] f16 (in-place)
  float*    out   = (float*)d_out;                     // [1024][64][256] f32
  float*    hidden= (float*)d_out + (size_t)1024*64*256;

  const int NC = 1024 / CT;
  k_gx0<<<dim3(CT, 2), dim3(512), 0, stream>>>(X, W_ih_f, b_ih_f, b_hh_f,
                                               W_ih_b, b_ih_b, b_hh_b, buf0, CT, 0);
  int flo = 512, fhi = 512;                  // fc'd interval [flo,fhi)
  for (int c = 0; c < NC; ++c) {
    _Float16* bin  = (c & 1) ? buf1 : buf0;
    _Float16* bout = (c & 1) ? buf0 : buf1;
    // rows complete before this launch: fwd [0,c*CT), bwd [1024-c*CT,1024)
    const int alo = 1024 - c*CT, ahi = c*CT;
    int b1 = 0, n1 = 0, b2 = 0, n2 = 0;
    if (ahi > alo) {
      if (alo < flo) { b1 = alo; n1 = flo - alo; }
      if (ahi > fhi) { b2 = fhi; n2 = ahi - fhi; }
      if (alo < flo) flo = alo;
      if (ahi > fhi) fhi = ahi;
    }
    k_step<<<dim3(8 + 2*CT + n1 + n2), dim3(512), 0, stream>>>(
        W_hh_f, b_hh_f, W_hh_b, b_hh_b, bin, wsh, h16, hidden, CT, c*CT,
        X, W_ih_f, b_ih_f, b_hh_f, W_ih_b, b_ih_b, b_hh_b,
        bout, (c+1)*CT, (c < NC-1) ? 1 : 0,
        W_fc, b_fc, out, b1, n1, b2);
  }
  // tail: [0,flo) and [fhi,1024)
  const int tn1 = flo, tn2 = 1024 - fhi;
  if (tn1 + tn2 > 0)
    k_fc_tail<<<dim3(tn1 + tn2), dim3(512), 0, stream>>>(h16, W_fc, b_fc, out,
                                                         0, tn1, fhi);
}